// Round 6
// baseline (2512.938 us; speedup 1.0000x reference)
//
#include <hip/hip_runtime.h>
#include <hip/hip_bf16.h>

// ============================================================================
// WindowAttention round 9 (= round 8 resubmit; r8 bench was an infra failure:
// "container failed twice", no kernel verdict; source re-audited for OOB /
// barrier / LDS-size faults — none found).
//
// Split-bf16 MFMA for the qkv GEMM.
// r7 post-mortem: 128 VGPR is the structural cap (152KB LDS -> 1 block/CU ->
// 2 waves/SIMD -> 256/2 regs); scalar qkv GEMM = ~53% of VALU issue slots.
// Fix: qkv via mfma_f32_16x16x32_bf16 on split operands (x=hi+lo, W=whi+wlo;
// 3 MFMAs, drop lo*lo ~2^-18) -> ~f32 precision at matrix-pipe cost.
//  - W pre-converted once to bf16 hi/lo in d_ws (830KB; ws_size-guarded with
//    fallback to the verified r7 kernel).
//  - x staged in LDS as bf16 hi/lo (2x 128x200 u16 = 102KB, <=2-way banks).
//    LDS total 157,952 B (fits 160 KiB; r7 ran 152,064 fine).
//  - per head-pass/wave: 108 MFMA + 12 ds_read_b128 + 72 global 16B frag
//    loads, replacing 4320 scalar fma + 270 VMEM loads per thread.
//  - fragment maps (guide-verified): A row=lane&15, k=(lane>>4)*8+i;
//    B col(Wrow)=lane&15, k contiguous (row-major W ok); C col=lane&15,
//    row=(lane>>4)*4+reg.
// Attention / merge / projection / epilogue: verbatim r6 (1 query, 4-way,
// no-spill). Pass-2 pos-enc: reconstruct x=hi+lo, add pb, re-split.
// ============================================================================

typedef unsigned short u16;
typedef unsigned int   u32;

#define NTOK 128
#define CDIM 180
#define NHEAD 6
#define KVSTR 36            // f32 k/v row stride (before skew)
#define KVSZ  4640
#define QSTR 36             // q rows in sq_s
#define SLSTR 33            // slab view stride within sq_s
#define XH   200            // u16 stride of split-x rows (400B, 16B aligned)
#define WROWS 1081          // 540 Wqs + 540 Wqm + 1 zero row
#define WCOL 192            // padded K (180 -> 192)
#define XSTR 188            // (fallback kernel) f32 x stride
#define QKSCALE 0.18257418583505536f   // 30^-0.5

typedef __attribute__((ext_vector_type(8))) short bf16x8v;
typedef __attribute__((ext_vector_type(4))) float f32x4v;

__device__ __forceinline__ float bflo(u32 u){ return __uint_as_float(u << 16); }
__device__ __forceinline__ float bfhi(u32 u){ return __uint_as_float(u & 0xFFFF0000u); }
__device__ __forceinline__ float bf2f(u16 v){ return __uint_as_float(((u32)v) << 16); }

// f32 -> bf16 round-to-nearest-even (finite inputs)
__device__ __forceinline__ u16 f2bf(float f){
  u32 u = __float_as_uint(f);
  u32 r = u + 0x7FFFu + ((u >> 16) & 1u);
  return (u16)(r >> 16);
}
__device__ __forceinline__ void split2(float f, u16& h, u16& l){
  h = f2bf(f);
  float rem = f - bf2f(h);
  l = f2bf(rem);
}

// skewed k/v row start: breaks same-bank aliasing of key-row streams
__device__ __forceinline__ int kvrow(int r){ return r * KVSTR + ((r >> 4) << 2); }

template<bool F32> __device__ __forceinline__ float ld1(const void* p, size_t i) {
  if constexpr (F32) return reinterpret_cast<const float*>(p)[i];
  else               return bf2f(reinterpret_cast<const u16*>(p)[i]);
}
template<bool F32> __device__ __forceinline__ float2 ld2(const void* p, size_t i) {
  if constexpr (F32) return *reinterpret_cast<const float2*>(reinterpret_cast<const float*>(p) + i);
  else {
    u32 r = *reinterpret_cast<const u32*>(reinterpret_cast<const u16*>(p) + i);
    return float2{bflo(r), bfhi(r)};
  }
}
template<bool F32> __device__ __forceinline__ float4 ld4(const void* p, size_t i) {
  if constexpr (F32) return *reinterpret_cast<const float4*>(reinterpret_cast<const float*>(p) + i);
  else {
    uint2 r = *reinterpret_cast<const uint2*>(reinterpret_cast<const u16*>(p) + i);
    return float4{bflo(r.x), bfhi(r.x), bflo(r.y), bfhi(r.y)};
  }
}

// on-the-fly sine position encoding value for column c, token-in-64 n64
__device__ __forceinline__ float posenc(int c, int n64) {
  int t = (c < 90) ? c : (c - 90);
  float e = (c < 90) ? (float)((n64 >> 3) + 1) : (float)((n64 & 7) + 1);
  float embed = e * 0.78539807f;                 // 2*pi / 8.000001
  float expo  = (float)(t & ~1) * (1.0f / 90.0f);
  float arg   = embed * exp2f(-13.2877124f * expo);  // 10000^-expo
  return (t & 1) ? cosf(arg) : sinf(arg);
}

// ---------------------------------------------------------------------------
// dtype detector (unchanged): flag=1 => bf16 inputs.
// ---------------------------------------------------------------------------
__global__ void detect_dtype(const u32* __restrict__ xw, int* __restrict__ flag) {
  __shared__ int cnt[256];
  int c = 0;
  for (int i = threadIdx.x; i < 4096; i += 256) {
    u32 e = (xw[i] >> 7) & 0xFF;
    c += (e >= 0x58 && e <= 0x90) ? 1 : 0;
  }
  cnt[threadIdx.x] = c;
  __syncthreads();
  if (threadIdx.x == 0) {
    int t = 0;
    for (int i = 0; i < 256; ++i) t += cnt[i];
    flag[0] = (t >= 2458) ? 1 : 0;
  }
}

// ---------------------------------------------------------------------------
// W -> bf16 hi/lo converter. Row layout: [0,540)=Wqs, [540,1080)=Wqm,
// 1080 = zeros (pad rows for o in [90,96)). Cols padded 180->192 with zeros.
// ---------------------------------------------------------------------------
__global__ void conv_w(const void* __restrict__ Wqs, const void* __restrict__ Wqm,
                       const int* __restrict__ flag,
                       u16* __restrict__ whi, u16* __restrict__ wlo) {
  const int r = blockIdx.x;       // 0..1080
  const int c = threadIdx.x;      // 0..191
  float v = 0.f;
  if (r < 1080 && c < 180) {
    const void* W = (r < 540) ? Wqs : Wqm;
    const int rr  = (r < 540) ? r : r - 540;
    v = flag[0] ? ld1<false>(W, (size_t)rr * 180 + c)
                : ld1<true >(W, (size_t)rr * 180 + c);
  }
  u16 h, l;
  split2(v, h, l);
  whi[r * WCOL + c] = h;
  wlo[r * WCOL + c] = l;
}

// ---------------------------------------------------------------------------
// main fused body (MFMA qkv), 512 threads
// ---------------------------------------------------------------------------
template<bool F32>
__device__ void body_mfma(const void* __restrict__ x,    // (1024,128,180)
                          const void* __restrict__ mask, // (64,128,128)
                          const void* __restrict__ rpb,  // (675,6)
                          const void* __restrict__ Wp,   // (180,360)
                          const void* __restrict__ bp,   // (180)
                          const u16* __restrict__ whi,
                          const u16* __restrict__ wlo,
                          float* __restrict__ out,       // f32
                          u16* xhi_s, u16* xlo_s,
                          float* k_s, float* v_s, float* sq_s)
{
  const int tid = threadIdx.x;
  const int b   = blockIdx.x;
  const int w64 = b & 63;
  const int n   = tid >> 2;        // attention: token (query)
  const int j   = tid & 3;         // attention: quarter lane

  // MFMA mapping
  const int wv  = tid >> 6;        // wave -> m-tile (tokens wv*16..+15)
  const int l15 = tid & 15;
  const int lk  = (tid & 63) >> 4; // k-group 0..3

  // projection ownership: 1 token x 45 out-cols
  const int rp = tid & 127;
  const int og = __builtin_amdgcn_readfirstlane(tid >> 7);
  float acc[45];
  #pragma unroll
  for (int o2 = 0; o2 < 45; ++o2) acc[o2] = 0.f;

  // self-attention bias i-coords for query n
  const int bi_d = n >> 6, bi_h = (n >> 3) & 7, bi_w = n & 7;

  // ---- stage x window into LDS as bf16 hi/lo ----
  {
    const size_t xbase = (size_t)b * (NTOK * CDIM);
    for (int i = tid; i < NTOK * 45; i += 512) {
      int r = i / 45, c4 = (i - r * 45) * 4;
      float4 f = ld4<F32>(x, xbase + (size_t)r * CDIM + c4);
      u16 h0,l0,h1,l1,h2,l2,h3,l3;
      split2(f.x, h0, l0); split2(f.y, h1, l1);
      split2(f.z, h2, l2); split2(f.w, h3, l3);
      u32* ph = reinterpret_cast<u32*>(&xhi_s[r * XH + c4]);
      u32* pl = reinterpret_cast<u32*>(&xlo_s[r * XH + c4]);
      ph[0] = (u32)h0 | ((u32)h1 << 16);
      ph[1] = (u32)h2 | ((u32)h3 << 16);
      pl[0] = (u32)l0 | ((u32)l1 << 16);
      pl[1] = (u32)l2 | ((u32)l3 << 16);
    }
    // zero pad cols 180..199
    for (int i = tid; i < NTOK * 10; i += 512) {
      int r = i / 10, c = 180 + (i - r * 10) * 2;
      *reinterpret_cast<u32*>(&xhi_s[r * XH + c]) = 0;
      *reinterpret_cast<u32*>(&xlo_s[r * XH + c]) = 0;
    }
    // one-time zero of k/v pad cols 30,31
    if (tid < NTOK) {
      const int kb = kvrow(tid);
      k_s[kb + 30] = 0.f; k_s[kb + 31] = 0.f;
      v_s[kb + 30] = 0.f; v_s[kb + 31] = 0.f;
    }
  }

  for (int pass = 0; pass < 2; ++pass) {
    const bool self = (pass == 0);
    if (!self) {
      __syncthreads();
      // x += pos-enc: reconstruct hi+lo, add, re-split (err ~2^-18)
      for (int i = tid; i < NTOK * 90; i += 512) {
        int r = i / 90, c = (i - r * 90) * 2;   // pair (c, c+1), never straddles 90
        int n64 = r & 63;
        u32 hw = *reinterpret_cast<u32*>(&xhi_s[r * XH + c]);
        u32 lw = *reinterpret_cast<u32*>(&xlo_s[r * XH + c]);
        float x0 = bflo(hw) + bflo(lw) + posenc(c,     n64);
        float x1 = bfhi(hw) + bfhi(lw) + posenc(c + 1, n64);
        u16 h0,l0,h1,l1;
        split2(x0, h0, l0); split2(x1, h1, l1);
        *reinterpret_cast<u32*>(&xhi_s[r * XH + c]) = (u32)h0 | ((u32)h1 << 16);
        *reinterpret_cast<u32*>(&xlo_s[r * XH + c]) = (u32)l0 | ((u32)l1 << 16);
      }
    }
    const int matbase = self ? 0 : 540;
    for (int h = 0; h < NHEAD; ++h) {
      __syncthreads();
      // ---------- qkv via split-bf16 MFMA: M=128, N=96, K=192 ----------
      {
        int rowoff[6];
        #pragma unroll
        for (int nt = 0; nt < 6; ++nt) {
          const int o  = nt * 16 + l15;
          const int g2 = o / 30;
          const int lr = o - g2 * 30;
          rowoff[nt] = ((o < 90) ? (matbase + g2 * 180 + h * 30 + lr) : 1080) * WCOL;
        }
        f32x4v am[6];
        #pragma unroll
        for (int nt = 0; nt < 6; ++nt) am[nt] = f32x4v{0.f, 0.f, 0.f, 0.f};
        const u16* xh = &xhi_s[(wv * 16 + l15) * XH];
        const u16* xl = &xlo_s[(wv * 16 + l15) * XH];
        #pragma unroll 2
        for (int ks = 0; ks < 6; ++ks) {
          const int k0 = lk * 8 + ks * 32;
          bf16x8v ahi = *reinterpret_cast<const bf16x8v*>(xh + k0);
          bf16x8v alo = *reinterpret_cast<const bf16x8v*>(xl + k0);
          #pragma unroll
          for (int nt = 0; nt < 6; ++nt) {
            bf16x8v bhi = *reinterpret_cast<const bf16x8v*>(whi + rowoff[nt] + k0);
            bf16x8v blo = *reinterpret_cast<const bf16x8v*>(wlo + rowoff[nt] + k0);
            am[nt] = __builtin_amdgcn_mfma_f32_16x16x32_bf16(ahi, bhi, am[nt], 0, 0, 0);
            am[nt] = __builtin_amdgcn_mfma_f32_16x16x32_bf16(alo, bhi, am[nt], 0, 0, 0);
            am[nt] = __builtin_amdgcn_mfma_f32_16x16x32_bf16(ahi, blo, am[nt], 0, 0, 0);
          }
        }
        // C write: col=lane&15 (=o), row=(lane>>4)*4+reg (=token)
        #pragma unroll
        for (int nt = 0; nt < 6; ++nt) {
          const int o = nt * 16 + l15;
          if (o < 90) {
            const int g2 = o / 30;
            const int lr = o - g2 * 30;
            #pragma unroll
            for (int r = 0; r < 4; ++r) {
              const int t = wv * 16 + lk * 4 + r;
              const float val = am[nt][r];
              if (g2 == 0)      sq_s[t * QSTR + lr] = val * QKSCALE;
              else if (g2 == 1) k_s[kvrow(t) + lr] = val;
              else              v_s[kvrow(t) + lr] = val;
            }
          }
        }
      }
      __syncthreads();
      // ---------- load this thread's q row from LDS ----------
      float qfull[32];
      {
        const float* qr = &sq_s[n * QSTR];
        #pragma unroll
        for (int kk = 0; kk < 7; ++kk) {
          float4 t4 = *reinterpret_cast<const float4*>(qr + 4 * kk);
          qfull[4*kk]   = t4.x; qfull[4*kk+1] = t4.y;
          qfull[4*kk+2] = t4.z; qfull[4*kk+3] = t4.w;
        }
        float2 t2 = *reinterpret_cast<const float2*>(qr + 28);
        qfull[28] = t2.x; qfull[29] = t2.y;
        qfull[30] = 0.f;  qfull[31] = 0.f;
      }
      // q reads must finish before anyone overwrites sq_s as slab
      __syncthreads();
      // ---------- attention: query n, key-range split 4 ways by j ----------
      float o[32];
      #pragma unroll
      for (int d = 0; d < 32; ++d) o[d] = 0.f;
      float m = -1e30f, l = 0.f;

      int jbeg, jcount, kbase;
      if (self) { jbeg = j * 32; jcount = 32; kbase = 0; }
      else      { jbeg = j * 16; jcount = 16; kbase = (n < 64) ? 64 : 0; }
      const int il = self ? n : (n & 63);
      const size_t mbase = (size_t)w64 * (NTOK * NTOK) + (size_t)il * NTOK;

      for (int jj = 0; jj < jcount; jj += 4) {
        const int jl = jbeg + jj;
        const int jg = kbase + jl;
        const float* kb = &k_s[kvrow(jg)];
        float s[4];
        #pragma unroll
        for (int u = 0; u < 4; ++u) {
          const float* kr = kb + u * KVSTR;
          float t0 = 0.f, t1 = 0.f, t2 = 0.f, t3 = 0.f;
          #pragma unroll
          for (int kk = 0; kk < 8; ++kk) {
            float4 kv = *reinterpret_cast<const float4*>(kr + 4 * kk);
            t0 = fmaf(qfull[4 * kk],     kv.x, t0);
            t1 = fmaf(qfull[4 * kk + 1], kv.y, t1);
            t2 = fmaf(qfull[4 * kk + 2], kv.z, t2);
            t3 = fmaf(qfull[4 * kk + 3], kv.w, t3);
          }
          float sv = (t0 + t1) + (t2 + t3);
          sv += ld1<F32>(mask, mbase + (size_t)(jl + u));
          if (self) {
            const int jv = jl + u;
            const int dj = jv >> 6, hj = (jv >> 3) & 7, wj = jv & 7;
            const int idx = (bi_d - dj + 1) * 225 + (bi_h - hj + 7) * 15 + (bi_w - wj + 7);
            sv += ld1<F32>(rpb, (size_t)idx * 6 + h);
          }
          s[u] = sv;
        }
        float M = fmaxf(fmaxf(fmaxf(s[0], s[1]), fmaxf(s[2], s[3])), m);
        float corr = __expf(m - M);
        float p0 = __expf(s[0] - M), p1 = __expf(s[1] - M);
        float p2 = __expf(s[2] - M), p3 = __expf(s[3] - M);
        l = l * corr + ((p0 + p1) + (p2 + p3));
        const float* v0 = &v_s[kvrow(jg)];
        const float* v1 = v0 + KVSTR;
        const float* v2 = v1 + KVSTR;
        const float* v3 = v2 + KVSTR;
        #pragma unroll
        for (int kk = 0; kk < 8; ++kk) {
          float4 a0 = *reinterpret_cast<const float4*>(v0 + 4 * kk);
          float4 a1 = *reinterpret_cast<const float4*>(v1 + 4 * kk);
          float4 a2 = *reinterpret_cast<const float4*>(v2 + 4 * kk);
          float4 a3 = *reinterpret_cast<const float4*>(v3 + 4 * kk);
          o[4*kk]   = fmaf(o[4*kk],   corr, fmaf(p0, a0.x, fmaf(p1, a1.x, fmaf(p2, a2.x, p3 * a3.x))));
          o[4*kk+1] = fmaf(o[4*kk+1], corr, fmaf(p0, a0.y, fmaf(p1, a1.y, fmaf(p2, a2.y, p3 * a3.y))));
          o[4*kk+2] = fmaf(o[4*kk+2], corr, fmaf(p0, a0.z, fmaf(p1, a1.z, fmaf(p2, a2.z, p3 * a3.z))));
          o[4*kk+3] = fmaf(o[4*kk+3], corr, fmaf(p0, a0.w, fmaf(p1, a1.w, fmaf(p2, a2.w, p3 * a3.w))));
        }
        m = M;
      }
      // ---------- 2-level butterfly merge; j==0 writes head-slab ----------
      {
        #pragma unroll
        for (int s2 = 1; s2 <= 2; s2 <<= 1) {
          float m2 = __shfl_xor(m, s2);
          float l2 = __shfl_xor(l, s2);
          float M  = fmaxf(m, m2);
          float e1 = __expf(m - M);
          float e2 = __expf(m2 - M);
          l = l * e1 + l2 * e2;
          #pragma unroll
          for (int d = 0; d < 30; ++d) {
            float o2v = __shfl_xor(o[d], s2);
            o[d] = o[d] * e1 + o2v * e2;
          }
          m = M;
        }
        if (j == 0) {
          const int r = self ? n : ((n + 64) & 127);   // mutual swaps halves
          float* srow = &sq_s[r * SLSTR];              // slab view
          const float inv = 1.0f / l;
          #pragma unroll
          for (int d = 0; d < 30; ++d) srow[d] = o[d] * inv;
        }
      }
      __syncthreads();
      // ---------- projection accumulate: slab @ Wp[:, cb:cb+30) ----------
      {
        const int cb = self ? (CDIM + h * 30) : (h * 30);
        float s0[30];
        #pragma unroll
        for (int d = 0; d < 30; ++d) s0[d] = sq_s[rp * SLSTR + d];
        const size_t wrow = (size_t)(og * 45) * 360 + cb;
        #pragma unroll
        for (int o2 = 0; o2 < 45; ++o2) {
          const size_t wr = wrow + (size_t)o2 * 360;
          float t0 = 0.f;
          #pragma unroll
          for (int d = 0; d < 30; d += 2) {
            float2 w2 = ld2<F32>(Wp, wr + d);
            t0 = fmaf(s0[d], w2.x, fmaf(s0[d + 1], w2.y, t0));
          }
          acc[o2] += t0;
        }
      }
    } // heads
  } // passes

  // ---- epilogue: + b_proj, write FLOAT32 ----
  {
    float* o0 = out + ((size_t)b * NTOK + rp) * CDIM + og * 45;
    #pragma unroll
    for (int o2 = 0; o2 < 45; ++o2) {
      float bb = ld1<F32>(bp, og * 45 + o2);
      o0[o2] = acc[o2] + bb;
    }
  }
}

__global__ __launch_bounds__(512) void fused_mfma(
    const void* __restrict__ x,    const void* __restrict__ mask,
    const void* __restrict__ rpb,  const void* __restrict__ Wp,
    const void* __restrict__ bp,   const int* __restrict__ flag,
    const u16* __restrict__ whi,   const u16* __restrict__ wlo,
    float* __restrict__ out)
{
  __shared__ __align__(16) u16 xhi_s[NTOK * XH];     // 51,200 B
  __shared__ __align__(16) u16 xlo_s[NTOK * XH];     // 51,200 B
  __shared__ __align__(16) float k_s[KVSZ];          // 18,560 B
  __shared__ __align__(16) float v_s[KVSZ];          // 18,560 B
  __shared__ __align__(16) float sq_s[NTOK * QSTR];  // 18,432 B -> 157,952 B
  if (flag[0]) body_mfma<false>(x, mask, rpb, Wp, bp, whi, wlo, out, xhi_s, xlo_s, k_s, v_s, sq_s);
  else         body_mfma<true >(x, mask, rpb, Wp, bp, whi, wlo, out, xhi_s, xlo_s, k_s, v_s, sq_s);
}

// ===========================================================================
// Fallback path (verified r7 kernel) — used only if ws_size is too small for
// the converted-W buffers.
// ===========================================================================
template<bool F32>
__device__ void body_old(const void* __restrict__ x, const void* __restrict__ mask,
                         const void* __restrict__ rpb, const void* __restrict__ Wqs,
                         const void* __restrict__ Wqm, const void* __restrict__ Wp,
                         const void* __restrict__ bp, float* __restrict__ out,
                         float* x_s, float* k_s, float* v_s, float* sq_s)
{
  const int tid = threadIdx.x;
  const int b   = blockIdx.x;
  const int w64 = b & 63;
  const int n   = tid >> 2;
  const int j   = tid & 3;
  const int nt  = tid & 31;
  const int ot  = tid >> 5;
  const bool act = (ot < 15);
  const int grp = ot / 5;
  const int lr0 = (ot - grp * 5) * 6;
  const int rp = tid & 127;
  const int og = __builtin_amdgcn_readfirstlane(tid >> 7);
  float acc[45];
  #pragma unroll
  for (int o2 = 0; o2 < 45; ++o2) acc[o2] = 0.f;
  const int bi_d = n >> 6, bi_h = (n >> 3) & 7, bi_w = n & 7;
  {
    const size_t xbase = (size_t)b * (NTOK * CDIM);
    for (int i = tid * 4; i < NTOK * CDIM; i += 2048) {
      float4 f = ld4<F32>(x, xbase + i);
      int r = i / CDIM, c = i - r * CDIM;
      float* dst = &x_s[r * XSTR + c];
      dst[0] = f.x; dst[1] = f.y; dst[2] = f.z; dst[3] = f.w;
    }
  }
  if (tid < NTOK) {
    const int kb = kvrow(tid);
    k_s[kb + 30] = 0.f; k_s[kb + 31] = 0.f;
    v_s[kb + 30] = 0.f; v_s[kb + 31] = 0.f;
  }
  for (int pass = 0; pass < 2; ++pass) {
    const bool self = (pass == 0);
    const void* W = self ? Wqs : Wqm;
    if (!self) {
      __syncthreads();
      for (int i = tid; i < NTOK * CDIM; i += 512) {
        int r = i / CDIM, c = i - r * CDIM;
        x_s[r * XSTR + c] += posenc(c, r & 63);
      }
    }
    for (int h = 0; h < NHEAD; ++h) {
      __syncthreads();
      if (act) {
        float a[4][6];
        #pragma unroll
        for (int i = 0; i < 4; ++i)
          #pragma unroll
          for (int rr = 0; rr < 6; ++rr) a[i][rr] = 0.f;
        const size_t wb = (size_t)(grp * 180 + h * 30 + lr0) * CDIM;
        const float* xr = &x_s[nt * XSTR];
        #pragma unroll 3
        for (int c = 0; c < CDIM; c += 4) {
          float4 wv[6];
          #pragma unroll
          for (int rr = 0; rr < 6; ++rr)
            wv[rr] = ld4<F32>(W, wb + (size_t)rr * CDIM + c);
          #pragma unroll
          for (int i = 0; i < 4; ++i) {
            float4 xv = *reinterpret_cast<const float4*>(xr + i * (32 * XSTR) + c);
            #pragma unroll
            for (int rr = 0; rr < 6; ++rr)
              a[i][rr] = fmaf(xv.x, wv[rr].x, fmaf(xv.y, wv[rr].y,
                         fmaf(xv.z, wv[rr].z, fmaf(xv.w, wv[rr].w, a[i][rr]))));
          }
        }
        #pragma unroll
        for (int i = 0; i < 4; ++i) {
          const int n2 = 32 * i + nt;
          #pragma unroll
          for (int rr = 0; rr < 6; ++rr) {
            const int lr = lr0 + rr;
            const float val = a[i][rr];
            if (grp == 0)      sq_s[n2 * QSTR + lr] = val * QKSCALE;
            else if (grp == 1) k_s[kvrow(n2) + lr] = val;
            else               v_s[kvrow(n2) + lr] = val;
          }
        }
      }
      __syncthreads();
      float qfull[32];
      {
        const float* qr = &sq_s[n * QSTR];
        #pragma unroll
        for (int kk = 0; kk < 7; ++kk) {
          float4 t4 = *reinterpret_cast<const float4*>(qr + 4 * kk);
          qfull[4*kk] = t4.x; qfull[4*kk+1] = t4.y;
          qfull[4*kk+2] = t4.z; qfull[4*kk+3] = t4.w;
        }
        float2 t2 = *reinterpret_cast<const float2*>(qr + 28);
        qfull[28] = t2.x; qfull[29] = t2.y; qfull[30] = 0.f; qfull[31] = 0.f;
      }
      __syncthreads();
      float o[32];
      #pragma unroll
      for (int d = 0; d < 32; ++d) o[d] = 0.f;
      float m = -1e30f, l = 0.f;
      int jbeg, jcount, kbase;
      if (self) { jbeg = j * 32; jcount = 32; kbase = 0; }
      else      { jbeg = j * 16; jcount = 16; kbase = (n < 64) ? 64 : 0; }
      const int il = self ? n : (n & 63);
      const size_t mbase = (size_t)w64 * (NTOK * NTOK) + (size_t)il * NTOK;
      for (int jj = 0; jj < jcount; jj += 4) {
        const int jl = jbeg + jj;
        const int jg = kbase + jl;
        const float* kb = &k_s[kvrow(jg)];
        float s[4];
        #pragma unroll
        for (int u = 0; u < 4; ++u) {
          const float* kr = kb + u * KVSTR;
          float t0 = 0.f, t1 = 0.f, t2 = 0.f, t3 = 0.f;
          #pragma unroll
          for (int kk = 0; kk < 8; ++kk) {
            float4 kv = *reinterpret_cast<const float4*>(kr + 4 * kk);
            t0 = fmaf(qfull[4 * kk],     kv.x, t0);
            t1 = fmaf(qfull[4 * kk + 1], kv.y, t1);
            t2 = fmaf(qfull[4 * kk + 2], kv.z, t2);
            t3 = fmaf(qfull[4 * kk + 3], kv.w, t3);
          }
          float sv = (t0 + t1) + (t2 + t3);
          sv += ld1<F32>(mask, mbase + (size_t)(jl + u));
          if (self) {
            const int jv = jl + u;
            const int dj = jv >> 6, hj = (jv >> 3) & 7, wj = jv & 7;
            const int idx = (bi_d - dj + 1) * 225 + (bi_h - hj + 7) * 15 + (bi_w - wj + 7);
            sv += ld1<F32>(rpb, (size_t)idx * 6 + h);
          }
          s[u] = sv;
        }
        float M = fmaxf(fmaxf(fmaxf(s[0], s[1]), fmaxf(s[2], s[3])), m);
        float corr = __expf(m - M);
        float p0 = __expf(s[0] - M), p1 = __expf(s[1] - M);
        float p2 = __expf(s[2] - M), p3 = __expf(s[3] - M);
        l = l * corr + ((p0 + p1) + (p2 + p3));
        const float* v0 = &v_s[kvrow(jg)];
        const float* v1 = v0 + KVSTR;
        const float* v2 = v1 + KVSTR;
        const float* v3 = v2 + KVSTR;
        #pragma unroll
        for (int kk = 0; kk < 8; ++kk) {
          float4 a0 = *reinterpret_cast<const float4*>(v0 + 4 * kk);
          float4 a1 = *reinterpret_cast<const float4*>(v1 + 4 * kk);
          float4 a2 = *reinterpret_cast<const float4*>(v2 + 4 * kk);
          float4 a3 = *reinterpret_cast<const float4*>(v3 + 4 * kk);
          o[4*kk]   = fmaf(o[4*kk],   corr, fmaf(p0, a0.x, fmaf(p1, a1.x, fmaf(p2, a2.x, p3 * a3.x))));
          o[4*kk+1] = fmaf(o[4*kk+1], corr, fmaf(p0, a0.y, fmaf(p1, a1.y, fmaf(p2, a2.y, p3 * a3.y))));
          o[4*kk+2] = fmaf(o[4*kk+2], corr, fmaf(p0, a0.z, fmaf(p1, a1.z, fmaf(p2, a2.z, p3 * a3.z))));
          o[4*kk+3] = fmaf(o[4*kk+3], corr, fmaf(p0, a0.w, fmaf(p1, a1.w, fmaf(p2, a2.w, p3 * a3.w))));
        }
        m = M;
      }
      {
        #pragma unroll
        for (int s2 = 1; s2 <= 2; s2 <<= 1) {
          float m2 = __shfl_xor(m, s2);
          float l2 = __shfl_xor(l, s2);
          float M  = fmaxf(m, m2);
          float e1 = __expf(m - M);
          float e2 = __expf(m2 - M);
          l = l * e1 + l2 * e2;
          #pragma unroll
          for (int d = 0; d < 30; ++d) {
            float o2v = __shfl_xor(o[d], s2);
            o[d] = o[d] * e1 + o2v * e2;
          }
          m = M;
        }
        if (j == 0) {
          const int r = self ? n : ((n + 64) & 127);
          float* srow = &sq_s[r * SLSTR];
          const float inv = 1.0f / l;
          #pragma unroll
          for (int d = 0; d < 30; ++d) srow[d] = o[d] * inv;
        }
      }
      __syncthreads();
      {
        const int cb = self ? (CDIM + h * 30) : (h * 30);
        float s0p[30];
        #pragma unroll
        for (int d = 0; d < 30; ++d) s0p[d] = sq_s[rp * SLSTR + d];
        const size_t wrow = (size_t)(og * 45) * 360 + cb;
        #pragma unroll
        for (int o2 = 0; o2 < 45; ++o2) {
          const size_t wr = wrow + (size_t)o2 * 360;
          float t0 = 0.f;
          #pragma unroll
          for (int d = 0; d < 30; d += 2) {
            float2 w2 = ld2<F32>(Wp, wr + d);
            t0 = fmaf(s0p[d], w2.x, fmaf(s0p[d + 1], w2.y, t0));
          }
          acc[o2] += t0;
        }
      }
    }
  }
  {
    float* o0 = out + ((size_t)b * NTOK + rp) * CDIM + og * 45;
    #pragma unroll
    for (int o2 = 0; o2 < 45; ++o2) {
      float bb = ld1<F32>(bp, og * 45 + o2);
      o0[o2] = acc[o2] + bb;
    }
  }
}

__global__ __launch_bounds__(512) void fused_all(
    const void* __restrict__ x,    const void* __restrict__ mask,
    const void* __restrict__ rpb,  const void* __restrict__ Wqs,
    const void* __restrict__ Wqm,  const void* __restrict__ Wp,
    const void* __restrict__ bp,   const int* __restrict__ flag,
    float* __restrict__ out)
{
  __shared__ __align__(16) float x_s[NTOK * XSTR];
  __shared__ __align__(16) float k_s[KVSZ];
  __shared__ __align__(16) float v_s[KVSZ];
  __shared__ __align__(16) float sq_s[NTOK * QSTR];
  if (flag[0]) body_old<false>(x, mask, rpb, Wqs, Wqm, Wp, bp, out, x_s, k_s, v_s, sq_s);
  else         body_old<true >(x, mask, rpb, Wqs, Wqm, Wp, bp, out, x_s, k_s, v_s, sq_s);
}

// ---------------------------------------------------------------------------
extern "C" void kernel_launch(void* const* d_in, const int* in_sizes, int n_in,
                              void* d_out, int out_size, void* d_ws, size_t ws_size,
                              hipStream_t stream) {
  int* flag = (int*)d_ws;
  detect_dtype<<<1, 256, 0, stream>>>((const u32*)d_in[0], flag);
  const size_t wbytes = (size_t)WROWS * WCOL * sizeof(u16);   // 415,104 B
  const size_t need = 64 + 2 * wbytes;                        // 830,272 B
  if (ws_size >= need) {
    u16* whi = (u16*)((char*)d_ws + 64);
    u16* wlo = (u16*)((char*)d_ws + 64 + wbytes);
    conv_w<<<WROWS, WCOL, 0, stream>>>(d_in[3], d_in[4], flag, whi, wlo);
    fused_mfma<<<1024, 512, 0, stream>>>(d_in[0], d_in[1], d_in[2], d_in[5],
                                         d_in[6], flag, whi, wlo, (float*)d_out);
  } else {
    fused_all<<<1024, 512, 0, stream>>>(d_in[0], d_in[1], d_in[2], d_in[3],
                                        d_in[4], d_in[5], d_in[6], flag,
                                        (float*)d_out);
  }
}

// Round 7
// 2003.963 us; speedup vs baseline: 1.2540x; 1.2540x over previous
//
#include <hip/hip_runtime.h>
#include <hip/hip_bf16.h>

// ============================================================================
// WindowAttention round 10: MFMA attention (S^T = K*Q^T, O^T = V^T*P).
// r9 post-mortem: removing qkv VALU (42->24% busy) changed dur 0% -> pacer is
// the serialized scalar-attention phase chain, not issue slots. Fix: attention
// on the matrix pipe with lane-shared fragments (LDS traffic 36MB -> ~2.5MB
// per block) and full-row softmax (2 shuffles, no online rescale).
//  - qkv MFMA writes q/k split-bf16 (u16 hi/lo bufs, stride 40 -> aligned
//    b128 frags), v packed u32 hi|lo (stride 37).
//  - S^T: A=k-tile, B=q-tile, 3 mfma/tile; lane holds query=l15, keys=(lk,r).
//  - P packed bf16 hi/lo in-register; 4-shuffles-per-word permutation into
//    PV B-frag layout (key 8lk+2j <- lane lk'=(2lk+(j>>1))&3, word j&1,
//    tile 2ks+(lk>>1); example-verified).
//  - O^T: A-frags = 8 u32 reads across keys; 1/L at slab write.
//  - slab aliases q bufs (q dead after S^T; in-attn barrier orders it).
//    q pad cols re-zeroed each pass (slab clobbers). 4 barriers/head-pass.
// LDS: x 102,400 + qbuf 20,480 + kbuf 20,480 + vbuf 18,944 = 162,304 B.
// Projection scalar (next target). Fallback r7 kernel behind ws guard.
// ============================================================================

typedef unsigned short u16;
typedef unsigned int   u32;

#define NTOK 128
#define CDIM 180
#define NHEAD 6
#define XH   200           // u16 stride of split-x rows
#define KQSTR 40           // u16 stride of q/k hi/lo rows (80B, 16B-aligned)
#define VSTR 37            // u32 stride of packed v rows
#define SLSTR 33           // f32 slab stride (aliases qbuf)
#define WROWS 1081
#define WCOL 192
#define XSTR 188           // fallback kernel f32 x stride
#define KVSTR 36           // fallback k/v stride
#define KVSZ  4640
#define QSTR 36            // fallback q stride
#define QKSCALE 0.18257418583505536f   // 30^-0.5

typedef __attribute__((ext_vector_type(8))) short bf16x8v;
typedef __attribute__((ext_vector_type(4))) float f32x4v;

__device__ __forceinline__ float bflo(u32 u){ return __uint_as_float(u << 16); }
__device__ __forceinline__ float bfhi(u32 u){ return __uint_as_float(u & 0xFFFF0000u); }
__device__ __forceinline__ float bf2f(u16 v){ return __uint_as_float(((u32)v) << 16); }

__device__ __forceinline__ u16 f2bf(float f){
  u32 u = __float_as_uint(f);
  u32 r = u + 0x7FFFu + ((u >> 16) & 1u);
  return (u16)(r >> 16);
}
__device__ __forceinline__ void split2(float f, u16& h, u16& l){
  h = f2bf(f);
  float rem = f - bf2f(h);
  l = f2bf(rem);
}

__device__ __forceinline__ int kvrow(int r){ return r * KVSTR + ((r >> 4) << 2); }

template<bool F32> __device__ __forceinline__ float ld1(const void* p, size_t i) {
  if constexpr (F32) return reinterpret_cast<const float*>(p)[i];
  else               return bf2f(reinterpret_cast<const u16*>(p)[i]);
}
template<bool F32> __device__ __forceinline__ float2 ld2(const void* p, size_t i) {
  if constexpr (F32) return *reinterpret_cast<const float2*>(reinterpret_cast<const float*>(p) + i);
  else {
    u32 r = *reinterpret_cast<const u32*>(reinterpret_cast<const u16*>(p) + i);
    return float2{bflo(r), bfhi(r)};
  }
}
template<bool F32> __device__ __forceinline__ float4 ld4(const void* p, size_t i) {
  if constexpr (F32) return *reinterpret_cast<const float4*>(reinterpret_cast<const float*>(p) + i);
  else {
    uint2 r = *reinterpret_cast<const uint2*>(reinterpret_cast<const u16*>(p) + i);
    return float4{bflo(r.x), bfhi(r.x), bflo(r.y), bfhi(r.y)};
  }
}

__device__ __forceinline__ float posenc(int c, int n64) {
  int t = (c < 90) ? c : (c - 90);
  float e = (c < 90) ? (float)((n64 >> 3) + 1) : (float)((n64 & 7) + 1);
  float embed = e * 0.78539807f;
  float expo  = (float)(t & ~1) * (1.0f / 90.0f);
  float arg   = embed * exp2f(-13.2877124f * expo);
  return (t & 1) ? cosf(arg) : sinf(arg);
}

// ---------------------------------------------------------------------------
__global__ void detect_dtype(const u32* __restrict__ xw, int* __restrict__ flag) {
  __shared__ int cnt[256];
  int c = 0;
  for (int i = threadIdx.x; i < 4096; i += 256) {
    u32 e = (xw[i] >> 7) & 0xFF;
    c += (e >= 0x58 && e <= 0x90) ? 1 : 0;
  }
  cnt[threadIdx.x] = c;
  __syncthreads();
  if (threadIdx.x == 0) {
    int t = 0;
    for (int i = 0; i < 256; ++i) t += cnt[i];
    flag[0] = (t >= 2458) ? 1 : 0;
  }
}

// ---------------------------------------------------------------------------
__global__ void conv_w(const void* __restrict__ Wqs, const void* __restrict__ Wqm,
                       const int* __restrict__ flag,
                       u16* __restrict__ whi, u16* __restrict__ wlo) {
  const int r = blockIdx.x;
  const int c = threadIdx.x;
  float v = 0.f;
  if (r < 1080 && c < 180) {
    const void* W = (r < 540) ? Wqs : Wqm;
    const int rr  = (r < 540) ? r : r - 540;
    v = flag[0] ? ld1<false>(W, (size_t)rr * 180 + c)
                : ld1<true >(W, (size_t)rr * 180 + c);
  }
  u16 h, l;
  split2(v, h, l);
  whi[r * WCOL + c] = h;
  wlo[r * WCOL + c] = l;
}

// ---------------------------------------------------------------------------
// MFMA attention for one head-pass. Wave owns query tile qb=wv*16.
// Contains one __syncthreads (post-S^T: all q/k reads done -> slab writable).
// ---------------------------------------------------------------------------
template<bool F32, bool SELF>
__device__ __forceinline__ void attn_phase(
    int h, const void* __restrict__ mask, const void* __restrict__ rpb,
    const u16* __restrict__ qhi, const u16* __restrict__ qlo,
    const u16* __restrict__ khi, const u16* __restrict__ klo,
    const u32* __restrict__ vbuf, float* __restrict__ slab,
    int w64, int qb, int l15, int lk)
{
  constexpr int NT  = SELF ? 8 : 4;   // 16-key tiles
  constexpr int NKS = SELF ? 4 : 2;   // 32-key PV steps
  const int query = qb + l15;
  const int kbase = SELF ? 0 : ((qb < 64) ? 64 : 0);

  // ---- S^T = K * Q^T (split-bf16, 3 mfma/tile) ----
  bf16x8v qfh = *reinterpret_cast<const bf16x8v*>(qhi + query * KQSTR + lk * 8);
  bf16x8v qfl = *reinterpret_cast<const bf16x8v*>(qlo + query * KQSTR + lk * 8);
  f32x4v sacc[NT];
  #pragma unroll
  for (int t = 0; t < NT; ++t) sacc[t] = f32x4v{0.f, 0.f, 0.f, 0.f};
  #pragma unroll
  for (int t = 0; t < NT; ++t) {
    const int krow = kbase + t * 16 + l15;
    bf16x8v kfh = *reinterpret_cast<const bf16x8v*>(khi + krow * KQSTR + lk * 8);
    bf16x8v kfl = *reinterpret_cast<const bf16x8v*>(klo + krow * KQSTR + lk * 8);
    sacc[t] = __builtin_amdgcn_mfma_f32_16x16x32_bf16(kfh, qfh, sacc[t], 0, 0, 0);
    sacc[t] = __builtin_amdgcn_mfma_f32_16x16x32_bf16(kfl, qfh, sacc[t], 0, 0, 0);
    sacc[t] = __builtin_amdgcn_mfma_f32_16x16x32_bf16(kfh, qfl, sacc[t], 0, 0, 0);
  }
  // all waves' q/k LDS reads complete; qbuf may be reused as slab after this
  __syncthreads();

  // ---- scale + mask (+rpb), row max ----
  const int il = SELF ? query : (query & 63);
  const size_t mbase = (size_t)w64 * (NTOK * NTOK) + (size_t)il * NTOK;
  const int bi_d = query >> 6, bi_h = (query >> 3) & 7, bi_w = query & 7;
  float mx = -1e30f;
  #pragma unroll
  for (int t = 0; t < NT; ++t) {
    float4 mv = ld4<F32>(mask, mbase + (size_t)(t * 16 + lk * 4));
    float mvr[4] = {mv.x, mv.y, mv.z, mv.w};
    #pragma unroll
    for (int r = 0; r < 4; ++r) {
      float sv = sacc[t][r] * QKSCALE + mvr[r];
      if (SELF) {
        const int jv = t * 16 + lk * 4 + r;
        const int dj = jv >> 6, hj = (jv >> 3) & 7, wj = jv & 7;
        const int idx = (bi_d - dj + 1) * 225 + (bi_h - hj + 7) * 15 + (bi_w - wj + 7);
        sv += ld1<F32>(rpb, (size_t)idx * 6 + h);
      }
      sacc[t][r] = sv;
      mx = fmaxf(mx, sv);
    }
  }
  mx = fmaxf(mx, __shfl_xor(mx, 16));
  mx = fmaxf(mx, __shfl_xor(mx, 32));

  // ---- exp, row sum, pack P into bf16 hi/lo pairs ----
  float L = 0.f;
  u32 ph[NT][2], pl[NT][2];
  #pragma unroll
  for (int t = 0; t < NT; ++t) {
    float p0 = __expf(sacc[t][0] - mx);
    float p1 = __expf(sacc[t][1] - mx);
    float p2 = __expf(sacc[t][2] - mx);
    float p3 = __expf(sacc[t][3] - mx);
    L += (p0 + p1) + (p2 + p3);
    u16 a0,b0,a1,b1,a2,b2,a3,b3;
    split2(p0,a0,b0); split2(p1,a1,b1); split2(p2,a2,b2); split2(p3,a3,b3);
    ph[t][0] = (u32)a0 | ((u32)a1 << 16);
    ph[t][1] = (u32)a2 | ((u32)a3 << 16);
    pl[t][0] = (u32)b0 | ((u32)b1 << 16);
    pl[t][1] = (u32)b2 | ((u32)b3 << 16);
  }
  L += __shfl_xor(L, 16);
  L += __shfl_xor(L, 32);
  const float invL = 1.0f / L;

  // ---- O^T = V^T * P (A across keys from packed vbuf; B via shuffles) ----
  f32x4v oacc0 = f32x4v{0.f, 0.f, 0.f, 0.f};
  f32x4v oacc1 = f32x4v{0.f, 0.f, 0.f, 0.f};
  #pragma unroll
  for (int ks = 0; ks < NKS; ++ks) {
    u32 wh[4], wl[4];
    #pragma unroll
    for (int jj = 0; jj < 4; ++jj) {
      const int lkp = (2 * lk + (jj >> 1)) & 3;
      const int src = l15 + (lkp << 4);
      u32 a = __shfl(ph[2 * ks][jj & 1], src);
      u32 b = __shfl(ph[2 * ks + 1][jj & 1], src);
      wh[jj] = (lk & 2) ? b : a;
      u32 c = __shfl(pl[2 * ks][jj & 1], src);
      u32 d = __shfl(pl[2 * ks + 1][jj & 1], src);
      wl[jj] = (lk & 2) ? d : c;
    }
    union UB { u32 w[4]; bf16x8v v; } BH, BL;
    BH.w[0] = wh[0]; BH.w[1] = wh[1]; BH.w[2] = wh[2]; BH.w[3] = wh[3];
    BL.w[0] = wl[0]; BL.w[1] = wl[1]; BL.w[2] = wl[2]; BL.w[3] = wl[3];
    #pragma unroll
    for (int mt = 0; mt < 2; ++mt) {
      u32 u[8];
      #pragma unroll
      for (int i = 0; i < 8; ++i)
        u[i] = vbuf[(size_t)(kbase + ks * 32 + lk * 8 + i) * VSTR + mt * 16 + l15];
      union UA { u32 w[4]; bf16x8v v; } AH, AL;
      #pragma unroll
      for (int jj = 0; jj < 4; ++jj) {
        AH.w[jj] = (u[2 * jj] & 0xFFFFu) | (u[2 * jj + 1] << 16);
        AL.w[jj] = (u[2 * jj] >> 16)     | (u[2 * jj + 1] & 0xFFFF0000u);
      }
      if (mt == 0) {
        oacc0 = __builtin_amdgcn_mfma_f32_16x16x32_bf16(AH.v, BH.v, oacc0, 0, 0, 0);
        oacc0 = __builtin_amdgcn_mfma_f32_16x16x32_bf16(AL.v, BH.v, oacc0, 0, 0, 0);
        oacc0 = __builtin_amdgcn_mfma_f32_16x16x32_bf16(AH.v, BL.v, oacc0, 0, 0, 0);
      } else {
        oacc1 = __builtin_amdgcn_mfma_f32_16x16x32_bf16(AH.v, BH.v, oacc1, 0, 0, 0);
        oacc1 = __builtin_amdgcn_mfma_f32_16x16x32_bf16(AL.v, BH.v, oacc1, 0, 0, 0);
        oacc1 = __builtin_amdgcn_mfma_f32_16x16x32_bf16(AH.v, BL.v, oacc1, 0, 0, 0);
      }
    }
  }

  // ---- O write: col=query(l15), row=dim=mt*16+lk*4+r ----
  const int orow = SELF ? query : ((query + 64) & 127);
  #pragma unroll
  for (int r = 0; r < 4; ++r) {
    const int d0 = lk * 4 + r;                 // < 16
    slab[orow * SLSTR + d0] = oacc0[r] * invL;
    const int d1 = 16 + d0;
    if (d1 < 30) slab[orow * SLSTR + d1] = oacc1[r] * invL;
  }
}

// ---------------------------------------------------------------------------
// main fused body (MFMA qkv + MFMA attention), 512 threads
// ---------------------------------------------------------------------------
template<bool F32>
__device__ void body_mfma(const void* __restrict__ x,
                          const void* __restrict__ mask,
                          const void* __restrict__ rpb,
                          const void* __restrict__ Wp,
                          const void* __restrict__ bp,
                          const u16* __restrict__ whi,
                          const u16* __restrict__ wlo,
                          float* __restrict__ out,
                          u16* xhi_s, u16* xlo_s,
                          u16* qbuf, u16* kbuf, u32* vbuf)
{
  const int tid = threadIdx.x;
  const int b   = blockIdx.x;
  const int w64 = b & 63;

  const int wv  = tid >> 6;        // wave id -> m/query tile
  const int l15 = tid & 15;
  const int lk  = (tid & 63) >> 4; // k-group 0..3
  const int qb  = wv * 16;

  u16* qhi = qbuf;
  u16* qlo = qbuf + NTOK * KQSTR;
  u16* khi = kbuf;
  u16* klo = kbuf + NTOK * KQSTR;
  float* slab = reinterpret_cast<float*>(qbuf);   // alias; q dead after S^T

  const int rp = tid & 127;
  const int og = __builtin_amdgcn_readfirstlane(tid >> 7);
  float acc[45];
  #pragma unroll
  for (int o2 = 0; o2 < 45; ++o2) acc[o2] = 0.f;

  // ---- stage x window into LDS as bf16 hi/lo ----
  {
    const size_t xbase = (size_t)b * (NTOK * CDIM);
    for (int i = tid; i < NTOK * 45; i += 512) {
      int r = i / 45, c4 = (i - r * 45) * 4;
      float4 f = ld4<F32>(x, xbase + (size_t)r * CDIM + c4);
      u16 h0,l0,h1,l1,h2,l2,h3,l3;
      split2(f.x, h0, l0); split2(f.y, h1, l1);
      split2(f.z, h2, l2); split2(f.w, h3, l3);
      u32* phd = reinterpret_cast<u32*>(&xhi_s[r * XH + c4]);
      u32* pld = reinterpret_cast<u32*>(&xlo_s[r * XH + c4]);
      phd[0] = (u32)h0 | ((u32)h1 << 16);
      phd[1] = (u32)h2 | ((u32)h3 << 16);
      pld[0] = (u32)l0 | ((u32)l1 << 16);
      pld[1] = (u32)l2 | ((u32)l3 << 16);
    }
    for (int i = tid; i < NTOK * 10; i += 512) {   // zero x pad cols 180..199
      int r = i / 10, c = 180 + (i - r * 10) * 2;
      *reinterpret_cast<u32*>(&xhi_s[r * XH + c]) = 0;
      *reinterpret_cast<u32*>(&xlo_s[r * XH + c]) = 0;
    }
    // one-time zero of k/v pad cols 30,31 (k/v bufs not clobbered by slab)
    if (tid < NTOK) {
      khi[tid * KQSTR + 30] = 0; khi[tid * KQSTR + 31] = 0;
      klo[tid * KQSTR + 30] = 0; klo[tid * KQSTR + 31] = 0;
      vbuf[tid * VSTR + 30] = 0; vbuf[tid * VSTR + 31] = 0;
    }
  }

  for (int pass = 0; pass < 2; ++pass) {
    const bool self = (pass == 0);
    if (!self) {
      __syncthreads();
      for (int i = tid; i < NTOK * 90; i += 512) {
        int r = i / 90, c = (i - r * 90) * 2;
        int n64 = r & 63;
        u32 hw = *reinterpret_cast<u32*>(&xhi_s[r * XH + c]);
        u32 lw = *reinterpret_cast<u32*>(&xlo_s[r * XH + c]);
        float x0 = bflo(hw) + bflo(lw) + posenc(c,     n64);
        float x1 = bfhi(hw) + bfhi(lw) + posenc(c + 1, n64);
        u16 h0,l0,h1,l1;
        split2(x0, h0, l0); split2(x1, h1, l1);
        *reinterpret_cast<u32*>(&xhi_s[r * XH + c]) = (u32)h0 | ((u32)h1 << 16);
        *reinterpret_cast<u32*>(&xlo_s[r * XH + c]) = (u32)l0 | ((u32)l1 << 16);
      }
    }
    const int matbase = self ? 0 : 540;
    for (int h = 0; h < NHEAD; ++h) {
      __syncthreads();   // head-top: projection's slab reads done, x stable
      // ---------- qkv via split-bf16 MFMA: M=128, N=96, K=192 ----------
      {
        int rowoff[6];
        #pragma unroll
        for (int nt = 0; nt < 6; ++nt) {
          const int o  = nt * 16 + l15;
          const int g2 = o / 30;
          const int lr = o - g2 * 30;
          rowoff[nt] = ((o < 90) ? (matbase + g2 * 180 + h * 30 + lr) : 1080) * WCOL;
        }
        f32x4v am[6];
        #pragma unroll
        for (int nt = 0; nt < 6; ++nt) am[nt] = f32x4v{0.f, 0.f, 0.f, 0.f};
        const u16* xh = &xhi_s[(wv * 16 + l15) * XH];
        const u16* xl = &xlo_s[(wv * 16 + l15) * XH];
        #pragma unroll 2
        for (int ks = 0; ks < 6; ++ks) {
          const int k0 = lk * 8 + ks * 32;
          bf16x8v ahi = *reinterpret_cast<const bf16x8v*>(xh + k0);
          bf16x8v alo = *reinterpret_cast<const bf16x8v*>(xl + k0);
          #pragma unroll
          for (int nt = 0; nt < 6; ++nt) {
            bf16x8v bhi = *reinterpret_cast<const bf16x8v*>(whi + rowoff[nt] + k0);
            bf16x8v blo = *reinterpret_cast<const bf16x8v*>(wlo + rowoff[nt] + k0);
            am[nt] = __builtin_amdgcn_mfma_f32_16x16x32_bf16(ahi, bhi, am[nt], 0, 0, 0);
            am[nt] = __builtin_amdgcn_mfma_f32_16x16x32_bf16(alo, bhi, am[nt], 0, 0, 0);
            am[nt] = __builtin_amdgcn_mfma_f32_16x16x32_bf16(ahi, blo, am[nt], 0, 0, 0);
          }
        }
        // C write: col(lane&15)=out-row o, row((lane>>4)*4+reg)=token
        #pragma unroll
        for (int nt = 0; nt < 6; ++nt) {
          const int o = nt * 16 + l15;
          if (o < 90) {
            const int g2 = o / 30;
            const int lr = o - g2 * 30;
            #pragma unroll
            for (int r = 0; r < 4; ++r) {
              const int t = wv * 16 + lk * 4 + r;
              u16 hh, ll;
              split2(am[nt][r], hh, ll);
              if (g2 == 0)      { qhi[t * KQSTR + lr] = hh; qlo[t * KQSTR + lr] = ll; }
              else if (g2 == 1) { khi[t * KQSTR + lr] = hh; klo[t * KQSTR + lr] = ll; }
              else              vbuf[t * VSTR + lr] = (u32)hh | ((u32)ll << 16);
            }
          }
        }
        // re-zero q pad cols (slab writes clobbered them last head-pass)
        if (tid < NTOK) {
          qhi[tid * KQSTR + 30] = 0; qhi[tid * KQSTR + 31] = 0;
          qlo[tid * KQSTR + 30] = 0; qlo[tid * KQSTR + 31] = 0;
        }
      }
      __syncthreads();   // q/k/v visible
      if (self) attn_phase<F32, true >(h, mask, rpb, qhi, qlo, khi, klo, vbuf, slab, w64, qb, l15, lk);
      else      attn_phase<F32, false>(h, mask, rpb, qhi, qlo, khi, klo, vbuf, slab, w64, qb, l15, lk);
      __syncthreads();   // slab visible
      // ---------- projection accumulate: slab @ Wp[:, cb:cb+30) ----------
      {
        const int cb = self ? (CDIM + h * 30) : (h * 30);
        float s0[30];
        #pragma unroll
        for (int d = 0; d < 30; ++d) s0[d] = slab[rp * SLSTR + d];
        const size_t wrow = (size_t)(og * 45) * 360 + cb;
        #pragma unroll
        for (int o2 = 0; o2 < 45; ++o2) {
          const size_t wr = wrow + (size_t)o2 * 360;
          float t0 = 0.f;
          #pragma unroll
          for (int d = 0; d < 30; d += 2) {
            float2 w2 = ld2<F32>(Wp, wr + d);
            t0 = fmaf(s0[d], w2.x, fmaf(s0[d + 1], w2.y, t0));
          }
          acc[o2] += t0;
        }
      }
    } // heads
  } // passes

  // ---- epilogue ----
  {
    float* o0 = out + ((size_t)b * NTOK + rp) * CDIM + og * 45;
    #pragma unroll
    for (int o2 = 0; o2 < 45; ++o2) {
      float bb = ld1<F32>(bp, og * 45 + o2);
      o0[o2] = acc[o2] + bb;
    }
  }
}

__global__ __launch_bounds__(512) void fused_mfma(
    const void* __restrict__ x,    const void* __restrict__ mask,
    const void* __restrict__ rpb,  const void* __restrict__ Wp,
    const void* __restrict__ bp,   const int* __restrict__ flag,
    const u16* __restrict__ whi,   const u16* __restrict__ wlo,
    float* __restrict__ out)
{
  __shared__ __align__(16) u16 xhi_s[NTOK * XH];       // 51,200 B
  __shared__ __align__(16) u16 xlo_s[NTOK * XH];       // 51,200 B
  __shared__ __align__(16) u16 qbuf[2 * NTOK * KQSTR]; // 20,480 B (hi, lo; slab alias)
  __shared__ __align__(16) u16 kbuf[2 * NTOK * KQSTR]; // 20,480 B
  __shared__ __align__(16) u32 vbuf[NTOK * VSTR];      // 18,944 B -> 162,304 B
  if (flag[0]) body_mfma<false>(x, mask, rpb, Wp, bp, whi, wlo, out, xhi_s, xlo_s, qbuf, kbuf, vbuf);
  else         body_mfma<true >(x, mask, rpb, Wp, bp, whi, wlo, out, xhi_s, xlo_s, qbuf, kbuf, vbuf);
}

// ===========================================================================
// Fallback path (verified r7 scalar kernel) — only if ws_size too small.
// ===========================================================================
template<bool F32>
__device__ void body_old(const void* __restrict__ x, const void* __restrict__ mask,
                         const void* __restrict__ rpb, const void* __restrict__ Wqs,
                         const void* __restrict__ Wqm, const void* __restrict__ Wp,
                         const void* __restrict__ bp, float* __restrict__ out,
                         float* x_s, float* k_s, float* v_s, float* sq_s)
{
  const int tid = threadIdx.x;
  const int b   = blockIdx.x;
  const int w64 = b & 63;
  const int n   = tid >> 2;
  const int j   = tid & 3;
  const int nt  = tid & 31;
  const int ot  = tid >> 5;
  const bool act = (ot < 15);
  const int grp = ot / 5;
  const int lr0 = (ot - grp * 5) * 6;
  const int rp = tid & 127;
  const int og = __builtin_amdgcn_readfirstlane(tid >> 7);
  float acc[45];
  #pragma unroll
  for (int o2 = 0; o2 < 45; ++o2) acc[o2] = 0.f;
  const int bi_d = n >> 6, bi_h = (n >> 3) & 7, bi_w = n & 7;
  {
    const size_t xbase = (size_t)b * (NTOK * CDIM);
    for (int i = tid * 4; i < NTOK * CDIM; i += 2048) {
      float4 f = ld4<F32>(x, xbase + i);
      int r = i / CDIM, c = i - r * CDIM;
      float* dst = &x_s[r * XSTR + c];
      dst[0] = f.x; dst[1] = f.y; dst[2] = f.z; dst[3] = f.w;
    }
  }
  if (tid < NTOK) {
    const int kb = kvrow(tid);
    k_s[kb + 30] = 0.f; k_s[kb + 31] = 0.f;
    v_s[kb + 30] = 0.f; v_s[kb + 31] = 0.f;
  }
  for (int pass = 0; pass < 2; ++pass) {
    const bool self = (pass == 0);
    const void* W = self ? Wqs : Wqm;
    if (!self) {
      __syncthreads();
      for (int i = tid; i < NTOK * CDIM; i += 512) {
        int r = i / CDIM, c = i - r * CDIM;
        x_s[r * XSTR + c] += posenc(c, r & 63);
      }
    }
    for (int h = 0; h < NHEAD; ++h) {
      __syncthreads();
      if (act) {
        float a[4][6];
        #pragma unroll
        for (int i = 0; i < 4; ++i)
          #pragma unroll
          for (int rr = 0; rr < 6; ++rr) a[i][rr] = 0.f;
        const size_t wb = (size_t)(grp * 180 + h * 30 + lr0) * CDIM;
        const float* xr = &x_s[nt * XSTR];
        #pragma unroll 3
        for (int c = 0; c < CDIM; c += 4) {
          float4 wv[6];
          #pragma unroll
          for (int rr = 0; rr < 6; ++rr)
            wv[rr] = ld4<F32>(W, wb + (size_t)rr * CDIM + c);
          #pragma unroll
          for (int i = 0; i < 4; ++i) {
            float4 xv = *reinterpret_cast<const float4*>(xr + i * (32 * XSTR) + c);
            #pragma unroll
            for (int rr = 0; rr < 6; ++rr)
              a[i][rr] = fmaf(xv.x, wv[rr].x, fmaf(xv.y, wv[rr].y,
                         fmaf(xv.z, wv[rr].z, fmaf(xv.w, wv[rr].w, a[i][rr]))));
          }
        }
        #pragma unroll
        for (int i = 0; i < 4; ++i) {
          const int n2 = 32 * i + nt;
          #pragma unroll
          for (int rr = 0; rr < 6; ++rr) {
            const int lr = lr0 + rr;
            const float val = a[i][rr];
            if (grp == 0)      sq_s[n2 * QSTR + lr] = val * QKSCALE;
            else if (grp == 1) k_s[kvrow(n2) + lr] = val;
            else               v_s[kvrow(n2) + lr] = val;
          }
        }
      }
      __syncthreads();
      float qfull[32];
      {
        const float* qr = &sq_s[n * QSTR];
        #pragma unroll
        for (int kk = 0; kk < 7; ++kk) {
          float4 t4 = *reinterpret_cast<const float4*>(qr + 4 * kk);
          qfull[4*kk] = t4.x; qfull[4*kk+1] = t4.y;
          qfull[4*kk+2] = t4.z; qfull[4*kk+3] = t4.w;
        }
        float2 t2 = *reinterpret_cast<const float2*>(qr + 28);
        qfull[28] = t2.x; qfull[29] = t2.y; qfull[30] = 0.f; qfull[31] = 0.f;
      }
      __syncthreads();
      float o[32];
      #pragma unroll
      for (int d = 0; d < 32; ++d) o[d] = 0.f;
      float m = -1e30f, l = 0.f;
      int jbeg, jcount, kbase;
      if (self) { jbeg = j * 32; jcount = 32; kbase = 0; }
      else      { jbeg = j * 16; jcount = 16; kbase = (n < 64) ? 64 : 0; }
      const int il = self ? n : (n & 63);
      const size_t mbase = (size_t)w64 * (NTOK * NTOK) + (size_t)il * NTOK;
      for (int jj = 0; jj < jcount; jj += 4) {
        const int jl = jbeg + jj;
        const int jg = kbase + jl;
        const float* kb = &k_s[kvrow(jg)];
        float s[4];
        #pragma unroll
        for (int u = 0; u < 4; ++u) {
          const float* kr = kb + u * KVSTR;
          float t0 = 0.f, t1 = 0.f, t2 = 0.f, t3 = 0.f;
          #pragma unroll
          for (int kk = 0; kk < 8; ++kk) {
            float4 kv = *reinterpret_cast<const float4*>(kr + 4 * kk);
            t0 = fmaf(qfull[4 * kk],     kv.x, t0);
            t1 = fmaf(qfull[4 * kk + 1], kv.y, t1);
            t2 = fmaf(qfull[4 * kk + 2], kv.z, t2);
            t3 = fmaf(qfull[4 * kk + 3], kv.w, t3);
          }
          float sv = (t0 + t1) + (t2 + t3);
          sv += ld1<F32>(mask, mbase + (size_t)(jl + u));
          if (self) {
            const int jv = jl + u;
            const int dj = jv >> 6, hj = (jv >> 3) & 7, wj = jv & 7;
            const int idx = (bi_d - dj + 1) * 225 + (bi_h - hj + 7) * 15 + (bi_w - wj + 7);
            sv += ld1<F32>(rpb, (size_t)idx * 6 + h);
          }
          s[u] = sv;
        }
        float M = fmaxf(fmaxf(fmaxf(s[0], s[1]), fmaxf(s[2], s[3])), m);
        float corr = __expf(m - M);
        float p0 = __expf(s[0] - M), p1 = __expf(s[1] - M);
        float p2 = __expf(s[2] - M), p3 = __expf(s[3] - M);
        l = l * corr + ((p0 + p1) + (p2 + p3));
        const float* v0 = &v_s[kvrow(jg)];
        const float* v1 = v0 + KVSTR;
        const float* v2 = v1 + KVSTR;
        const float* v3 = v2 + KVSTR;
        #pragma unroll
        for (int kk = 0; kk < 8; ++kk) {
          float4 a0 = *reinterpret_cast<const float4*>(v0 + 4 * kk);
          float4 a1 = *reinterpret_cast<const float4*>(v1 + 4 * kk);
          float4 a2 = *reinterpret_cast<const float4*>(v2 + 4 * kk);
          float4 a3 = *reinterpret_cast<const float4*>(v3 + 4 * kk);
          o[4*kk]   = fmaf(o[4*kk],   corr, fmaf(p0, a0.x, fmaf(p1, a1.x, fmaf(p2, a2.x, p3 * a3.x))));
          o[4*kk+1] = fmaf(o[4*kk+1], corr, fmaf(p0, a0.y, fmaf(p1, a1.y, fmaf(p2, a2.y, p3 * a3.y))));
          o[4*kk+2] = fmaf(o[4*kk+2], corr, fmaf(p0, a0.z, fmaf(p1, a1.z, fmaf(p2, a2.z, p3 * a3.z))));
          o[4*kk+3] = fmaf(o[4*kk+3], corr, fmaf(p0, a0.w, fmaf(p1, a1.w, fmaf(p2, a2.w, p3 * a3.w))));
        }
        m = M;
      }
      {
        #pragma unroll
        for (int s2 = 1; s2 <= 2; s2 <<= 1) {
          float m2 = __shfl_xor(m, s2);
          float l2 = __shfl_xor(l, s2);
          float M  = fmaxf(m, m2);
          float e1 = __expf(m - M);
          float e2 = __expf(m2 - M);
          l = l * e1 + l2 * e2;
          #pragma unroll
          for (int d = 0; d < 30; ++d) {
            float o2v = __shfl_xor(o[d], s2);
            o[d] = o[d] * e1 + o2v * e2;
          }
          m = M;
        }
        if (j == 0) {
          const int r = self ? n : ((n + 64) & 127);
          float* srow = &sq_s[r * SLSTR];
          const float inv = 1.0f / l;
          #pragma unroll
          for (int d = 0; d < 30; ++d) srow[d] = o[d] * inv;
        }
      }
      __syncthreads();
      {
        const int cb = self ? (CDIM + h * 30) : (h * 30);
        float s0p[30];
        #pragma unroll
        for (int d = 0; d < 30; ++d) s0p[d] = sq_s[rp * SLSTR + d];
        const size_t wrow = (size_t)(og * 45) * 360 + cb;
        #pragma unroll
        for (int o2 = 0; o2 < 45; ++o2) {
          const size_t wr = wrow + (size_t)o2 * 360;
          float t0 = 0.f;
          #pragma unroll
          for (int d = 0; d < 30; d += 2) {
            float2 w2 = ld2<F32>(Wp, wr + d);
            t0 = fmaf(s0p[d], w2.x, fmaf(s0p[d + 1], w2.y, t0));
          }
          acc[o2] += t0;
        }
      }
    }
  }
  {
    float* o0 = out + ((size_t)b * NTOK + rp) * CDIM + og * 45;
    #pragma unroll
    for (int o2 = 0; o2 < 45; ++o2) {
      float bb = ld1<F32>(bp, og * 45 + o2);
      o0[o2] = acc[o2] + bb;
    }
  }
}

__global__ __launch_bounds__(512) void fused_all(
    const void* __restrict__ x,    const void* __restrict__ mask,
    const void* __restrict__ rpb,  const void* __restrict__ Wqs,
    const void* __restrict__ Wqm,  const void* __restrict__ Wp,
    const void* __restrict__ bp,   const int* __restrict__ flag,
    float* __restrict__ out)
{
  __shared__ __align__(16) float x_s[NTOK * XSTR];
  __shared__ __align__(16) float k_s[KVSZ];
  __shared__ __align__(16) float v_s[KVSZ];
  __shared__ __align__(16) float sq_s[NTOK * QSTR];
  if (flag[0]) body_old<false>(x, mask, rpb, Wqs, Wqm, Wp, bp, out, x_s, k_s, v_s, sq_s);
  else         body_old<true >(x, mask, rpb, Wqs, Wqm, Wp, bp, out, x_s, k_s, v_s, sq_s);
}

// ---------------------------------------------------------------------------
extern "C" void kernel_launch(void* const* d_in, const int* in_sizes, int n_in,
                              void* d_out, int out_size, void* d_ws, size_t ws_size,
                              hipStream_t stream) {
  int* flag = (int*)d_ws;
  detect_dtype<<<1, 256, 0, stream>>>((const u32*)d_in[0], flag);
  const size_t wbytes = (size_t)WROWS * WCOL * sizeof(u16);   // 415,104 B
  const size_t need = 64 + 2 * wbytes;                        // 830,272 B
  if (ws_size >= need) {
    u16* whi = (u16*)((char*)d_ws + 64);
    u16* wlo = (u16*)((char*)d_ws + 64 + wbytes);
    conv_w<<<WROWS, WCOL, 0, stream>>>(d_in[3], d_in[4], flag, whi, wlo);
    fused_mfma<<<1024, 512, 0, stream>>>(d_in[0], d_in[1], d_in[2], d_in[5],
                                         d_in[6], flag, whi, wlo, (float*)d_out);
  } else {
    fused_all<<<1024, 512, 0, stream>>>(d_in[0], d_in[1], d_in[2], d_in[3],
                                        d_in[4], d_in[5], d_in[6], flag,
                                        (float*)d_out);
  }
}